// Round 7
// baseline (7843.442 us; speedup 1.0000x reference)
//
#include <hip/hip_runtime.h>
#include <hip/hip_bf16.h>

#define DIMS 1024
#define SEQ 512
#define BATCH 128
#define VOCAB 32000
#define GRID 256

typedef __attribute__((ext_vector_type(8))) short short8;
typedef __attribute__((ext_vector_type(4))) float f32x4;

__device__ __forceinline__ ushort f2bf(float x) {
    union { float f; unsigned u; } v; v.f = x;
    unsigned u = v.u;
    return (ushort)((u + 0x7FFFu + ((u >> 16) & 1u)) >> 16);
}

__global__ void conv_emb_kernel(const float* __restrict__ in, ushort* __restrict__ out, int n) {
    int idx = blockIdx.x * blockDim.x + threadIdx.x;
    int stride = gridDim.x * blockDim.x;
    for (int i = idx * 4; i < n; i += stride * 4) {
        float4 v = *(const float4*)(in + i);
        ushort4 o;
        o.x = f2bf(v.x); o.y = f2bf(v.y); o.z = f2bf(v.z); o.w = f2bf(v.w);
        *(ushort4*)(out + i) = o;
    }
}

// Persistent LSTM, fence-free flag sync, K-split h@U, BATCHED loads.
// Grid = 256 blocks x 768 threads = 2 row-groups (64 rows) x 128 d-chunks.
// Waves 0-3  : x@W, full K=1024 (2 rounds of 16 batched cached loads) -> preX
// Waves 4-7  : h@U, K=0..511    (16 batched sc0/sc1 loads)           -> preH0
// Waves 8-11 : h@U, K=512..1023 (16 batched sc0/sc1 loads)           -> preH1
// Batched issue + single vmcnt(0) turns ~900-cyc-serialized loads into one
// latency exposure per round (the R5 profile showed ~450 cyc/iter = no MLP).
__launch_bounds__(768, 3)
__global__ void lstm_kernel(const int* __restrict__ feats,
                            const ushort* __restrict__ emb,
                            const float* __restrict__ Wf, const float* __restrict__ Uf, const float* __restrict__ bfp,
                            const float* __restrict__ Wi, const float* __restrict__ Ui, const float* __restrict__ bip,
                            const float* __restrict__ Wo, const float* __restrict__ Uo, const float* __restrict__ bop,
                            const float* __restrict__ Wc, const float* __restrict__ Uc, const float* __restrict__ bcp,
                            ushort* __restrict__ hbuf, float* __restrict__ out, int* __restrict__ flags) {
    __shared__ ushort Bl[32 * 2048];        // 131072 B: B-slice, XOR-swizzled
    __shared__ float preX[64 * 36];         // x@W preacts (pitch 36: conflict-free)
    __shared__ float preH0[64 * 36];        // h@U partial, K-half 0
    __shared__ float preH1[64 * 36];        // h@U partial, K-half 1

    const int tid = threadIdx.x;
    const int bid = blockIdx.x;
    const int rg = bid >> 7;      // row group: rows rg*64 .. rg*64+63
    const int cb = bid & 127;     // d-chunk: d = cb*8 .. cb*8+7

    // ---- one-time: load B slice (f32 -> bf16) into LDS ----
    for (int idx = tid; idx < 32 * 2048; idx += 768) {
        int cl = idx & 31;
        int k  = idx >> 5;
        int g  = cl >> 3, dd0 = cl & 7;
        int dw = cb * 8 + dd0;
        const float* Wg = (g == 0) ? Wf : (g == 1) ? Wi : (g == 2) ? Wo : Wc;
        const float* Ug = (g == 0) ? Uf : (g == 1) ? Ui : (g == 2) ? Uo : Uc;
        float v = (k < 1024) ? Wg[k * 1024 + dw] : Ug[(k - 1024) * 1024 + dw];
        int boff = ((cl << 12) | (k << 1)) ^ ((cl & 7) << 4);
        *(ushort*)((char*)Bl + boff) = f2bf(v);
    }

    const int lane = tid & 63;
    const int w  = tid >> 6;                 // wave 0..11
    const int role = (w < 4) ? 0 : (w < 8 ? 1 : 2);
    const int w4 = w & 3;                    // row sub-group
    const int lx = lane & 15;
    const int qq = lane >> 4;
    const int kg = qq * 8;
    const int lr = w4 * 16 + lx;             // local row within row-group
    const int brow = rg * 64 + lr;           // global batch row

    const int bofs0 = (lx << 12) ^ ((lx & 7) << 4);
    const int bofs1 = ((16 + lx) << 12) ^ ((lx & 7) << 4);

    const int kh    = (role == 2) ? 1 : 0;   // h K-half for roles 1/2
    const int fbase = kh * 64;               // producer flag range base
    float* myPre = (role == 0) ? preX : (role == 1) ? preH0 : preH1;
    const int r0 = w4 * 16 + qq * 4;         // C/D row base (col = lx, row = r0+reg)

    // gate-phase mapping (threads 0..511): row = tid>>3, dd = tid&7
    const int grow_ = tid >> 3;
    const int gdd   = tid & 7;
    const int gd    = cb * 8 + gdd;
    const float bF = bfp[gd], bI = bip[gd], bO = bop[gd], bC = bcp[gd];

    float cst = 0.f;
    int* myflags = flags + rg * 128;
    int fidx = (role == 0) ? feats[brow * SEQ] : 0;

    __syncthreads();   // Bl ready

    for (int t = 0; t < SEQ; t++) {
        f32x4 a00 = {0,0,0,0}, a01 = {0,0,0,0};   // n-tile 0, even/odd k-step
        f32x4 a10 = {0,0,0,0}, a11 = {0,0,0,0};   // n-tile 1, even/odd k-step

        if (role == 0) {
            // ---- x @ W, K = 0..1023, 2 rounds of 16 batched loads ----
            const ushort* xrow = emb + (size_t)fidx * DIMS;
            fidx = (t + 1 < SEQ) ? feats[brow * SEQ + t + 1] : 0;
            #pragma unroll
            for (int half = 0; half < 2; half++) {
                short8 xv[16];
                #pragma unroll
                for (int i = 0; i < 16; i++) {
                    const ushort* xp = xrow + (half * 16 + i) * 32 + kg;
                    asm volatile("global_load_dwordx4 %0, %1, off"
                                 : "=v"(xv[i]) : "v"(xp));
                }
                asm volatile("s_waitcnt vmcnt(0)" ::: "memory");
                __builtin_amdgcn_sched_barrier(0);
                #pragma unroll
                for (int i = 0; i < 16; i += 2) {
                    int k0 = (half * 16 + i) * 32 + kg;
                    short8 b0 = *(const short8*)((const char*)Bl + (bofs0 ^ (k0 << 1)));
                    short8 b1 = *(const short8*)((const char*)Bl + (bofs1 ^ (k0 << 1)));
                    a00 = __builtin_amdgcn_mfma_f32_16x16x32_bf16(xv[i], b0, a00, 0, 0, 0);
                    a10 = __builtin_amdgcn_mfma_f32_16x16x32_bf16(xv[i], b1, a10, 0, 0, 0);
                    int k1 = k0 + 32;
                    short8 b2 = *(const short8*)((const char*)Bl + (bofs0 ^ (k1 << 1)));
                    short8 b3 = *(const short8*)((const char*)Bl + (bofs1 ^ (k1 << 1)));
                    a01 = __builtin_amdgcn_mfma_f32_16x16x32_bf16(xv[i + 1], b2, a01, 0, 0, 0);
                    a11 = __builtin_amdgcn_mfma_f32_16x16x32_bf16(xv[i + 1], b3, a11, 0, 0, 0);
                }
            }
        } else if (t > 0) {
            // ---- poll my 64 producers ----
            long guard = 0;
            for (;;) {
                int f0 = __hip_atomic_load(myflags + fbase + lane, __ATOMIC_RELAXED, __HIP_MEMORY_SCOPE_AGENT);
                if (__all(f0 >= t)) break;
                __builtin_amdgcn_s_sleep(1);
                if (++guard > 100000000L) break;  // deadlock safety valve
            }
            // ---- h @ U for my K-half: 16 batched coherent loads ----
            const ushort* hbase = hbuf + (size_t)((t & 1) * 2 + rg) * (128 * 512);
            short8 hv[16];
            #pragma unroll
            for (int i = 0; i < 16; i++) {
                const ushort* hp = hbase + ((fbase + i * 4 + qq) << 9) + lr * 8;
                asm volatile("global_load_dwordx4 %0, %1, off sc0 sc1"
                             : "=v"(hv[i]) : "v"(hp));
            }
            asm volatile("s_waitcnt vmcnt(0)" ::: "memory");
            __builtin_amdgcn_sched_barrier(0);
            #pragma unroll
            for (int i = 0; i < 16; i += 2) {
                int k0 = 1024 + kh * 512 + i * 32 + kg;
                short8 b0 = *(const short8*)((const char*)Bl + (bofs0 ^ (k0 << 1)));
                short8 b1 = *(const short8*)((const char*)Bl + (bofs1 ^ (k0 << 1)));
                a00 = __builtin_amdgcn_mfma_f32_16x16x32_bf16(hv[i], b0, a00, 0, 0, 0);
                a10 = __builtin_amdgcn_mfma_f32_16x16x32_bf16(hv[i], b1, a10, 0, 0, 0);
                int k1 = k0 + 32;
                short8 b2 = *(const short8*)((const char*)Bl + (bofs0 ^ (k1 << 1)));
                short8 b3 = *(const short8*)((const char*)Bl + (bofs1 ^ (k1 << 1)));
                a01 = __builtin_amdgcn_mfma_f32_16x16x32_bf16(hv[i + 1], b2, a01, 0, 0, 0);
                a11 = __builtin_amdgcn_mfma_f32_16x16x32_bf16(hv[i + 1], b3, a11, 0, 0, 0);
            }
        }

        // ---- write partials (C/D layout: col = lane&15, row = (lane>>4)*4 + reg) ----
        #pragma unroll
        for (int j = 0; j < 4; j++) {
            myPre[(r0 + j) * 36 + lx]      = a00[j] + a01[j];
            myPre[(r0 + j) * 36 + 16 + lx] = a10[j] + a11[j];
        }
        __syncthreads();   // sync A: preX, preH0, preH1 complete

        // ---- gates: threads 0..511, 1 state each ----
        if (tid < 512) {
            int base = grow_ * 36;
            float pf = preX[base + gdd]      + preH0[base + gdd]      + preH1[base + gdd]      + bF;
            float pi = preX[base + 8 + gdd]  + preH0[base + 8 + gdd]  + preH1[base + 8 + gdd]  + bI;
            float po = preX[base + 16 + gdd] + preH0[base + 16 + gdd] + preH1[base + 16 + gdd] + bO;
            float pc = preX[base + 24 + gdd] + preH0[base + 24 + gdd] + preH1[base + 24 + gdd] + bC;
            float f  = 1.f / (1.f + __expf(-pf));
            float ig = 1.f / (1.f + __expf(-pi));
            float o  = 1.f / (1.f + __expf(-po));
            float e2 = __expf(2.f * pc);
            float cc = (e2 - 1.f) / (e2 + 1.f);
            float cn = f * cst + ig * cc;
            cst = cn;
            float e2c = __expf(2.f * cn);
            float th  = (e2c - 1.f) / (e2c + 1.f);
            float h   = o * th;
            if (t < SEQ - 1) {
                // coalesced: thread tid -> hnext[cb*512 + tid]
                ushort* hw = hbuf + (size_t)(((t + 1) & 1) * 2 + rg) * (128 * 512) + cb * 512 + tid;
                __hip_atomic_store(hw, f2bf(h), __ATOMIC_RELAXED, __HIP_MEMORY_SCOPE_AGENT);
            } else {
                int gr = rg * 64 + grow_;
                out[gr * 2048 + gd] = h;
                out[gr * 2048 + 1024 + gd] = cn;
            }
        }

        if (t < SEQ - 1) {
            asm volatile("s_waitcnt vmcnt(0)" ::: "memory");  // h stores acked at coherence point
            __syncthreads();                                   // sync B: publishes done; pre[] reusable
            if (tid == 0) {
                __hip_atomic_store(myflags + cb, t + 1, __ATOMIC_RELAXED, __HIP_MEMORY_SCOPE_AGENT);
            }
        }
    }
}

extern "C" void kernel_launch(void* const* d_in, const int* in_sizes, int n_in,
                              void* d_out, int out_size, void* d_ws, size_t ws_size,
                              hipStream_t stream) {
    const int*   feats = (const int*)d_in[0];
    const float* emb_f = (const float*)d_in[1];
    const float* Wf = (const float*)d_in[2];
    const float* Uf = (const float*)d_in[3];
    const float* bf_ = (const float*)d_in[4];
    const float* Wi = (const float*)d_in[5];
    const float* Ui = (const float*)d_in[6];
    const float* bi_ = (const float*)d_in[7];
    const float* Wo = (const float*)d_in[8];
    const float* Uo = (const float*)d_in[9];
    const float* bo_ = (const float*)d_in[10];
    const float* Wc = (const float*)d_in[11];
    const float* Uc = (const float*)d_in[12];
    const float* bc_ = (const float*)d_in[13];

    char* ws = (char*)d_ws;
    ushort* emb_bf = (ushort*)ws;                          // 65,536,000 B
    ushort* hbuf   = (ushort*)(ws + 65536000);             // 2x2x128x64x8 bf16 = 524,288 B
    int*    flags  = (int*)(ws + 65536000 + 524288);       // 256 flags

    hipMemsetAsync(flags, 0, 1024, stream);
    conv_emb_kernel<<<1024, 256, 0, stream>>>(emb_f, emb_bf, VOCAB * DIMS);
    lstm_kernel<<<GRID, 768, 0, stream>>>(feats, emb_bf,
                                          Wf, Uf, bf_, Wi, Ui, bi_,
                                          Wo, Uo, bo_, Wc, Uc, bc_,
                                          hbuf, (float*)d_out, flags);
}

// Round 8
// 4031.805 us; speedup vs baseline: 1.9454x; 1.9454x over previous
//
#include <hip/hip_runtime.h>
#include <hip/hip_bf16.h>

#define DIMS 1024
#define SEQ 512
#define BATCH 128
#define VOCAB 32000
#define GRID 256

typedef __attribute__((ext_vector_type(8))) short short8;
typedef __attribute__((ext_vector_type(4))) float f32x4;

__device__ __forceinline__ ushort f2bf(float x) {
    union { float f; unsigned u; } v; v.f = x;
    unsigned u = v.u;
    return (ushort)((u + 0x7FFFu + ((u >> 16) & 1u)) >> 16);
}

__global__ void conv_emb_kernel(const float* __restrict__ in, ushort* __restrict__ out, int n) {
    int idx = blockIdx.x * blockDim.x + threadIdx.x;
    int stride = gridDim.x * blockDim.x;
    for (int i = idx * 4; i < n; i += stride * 4) {
        float4 v = *(const float4*)(in + i);
        ushort4 o;
        o.x = f2bf(v.x); o.y = f2bf(v.y); o.z = f2bf(v.z); o.w = f2bf(v.w);
        *(ushort4*)(out + i) = o;
    }
}

// Persistent LSTM, fence-free flag sync, HOMOGENEOUS waves with K-split.
// Grid = 256 blocks x 512 threads = 2 row-groups (64 rows) x 128 d-chunks.
// 8 waves = 4 row-quarters (wr) x 2 K-halves (kh). Every wave runs the SAME
// schedule (R3's shape, halved): x@W(K-half, 16 iters) -> poll own half's
// 64 producers -> h@U(K-half, 16 iters, same accs) -> partial preacts to
// LDS -> barrier -> gates -> publish -> flag. Serial chain = 32 iters
// (vs R3's 64) at 2 waves/SIMD TLP; poll sits after useful x-work.
__launch_bounds__(512, 2)
__global__ void lstm_kernel(const int* __restrict__ feats,
                            const ushort* __restrict__ emb,
                            const float* __restrict__ Wf, const float* __restrict__ Uf, const float* __restrict__ bfp,
                            const float* __restrict__ Wi, const float* __restrict__ Ui, const float* __restrict__ bip,
                            const float* __restrict__ Wo, const float* __restrict__ Uo, const float* __restrict__ bop,
                            const float* __restrict__ Wc, const float* __restrict__ Uc, const float* __restrict__ bcp,
                            ushort* __restrict__ hbuf, float* __restrict__ out, int* __restrict__ flags) {
    __shared__ ushort Bl[32 * 2048];        // 131072 B: B-slice, XOR-swizzled
    __shared__ float pre0[64 * 36];         // K-half 0 partial (x+h), pitch 36
    __shared__ float pre1[64 * 36];         // K-half 1 partial (x+h)

    const int tid = threadIdx.x;
    const int bid = blockIdx.x;
    const int rg = bid >> 7;      // row group: rows rg*64 .. rg*64+63
    const int cb = bid & 127;     // d-chunk: d = cb*8 .. cb*8+7

    // ---- one-time: load B slice (f32 -> bf16) into LDS ----
    for (int idx = tid; idx < 32 * 2048; idx += 512) {
        int cl = idx & 31;
        int k  = idx >> 5;
        int g  = cl >> 3, dd0 = cl & 7;
        int dw = cb * 8 + dd0;
        const float* Wg = (g == 0) ? Wf : (g == 1) ? Wi : (g == 2) ? Wo : Wc;
        const float* Ug = (g == 0) ? Uf : (g == 1) ? Ui : (g == 2) ? Uo : Uc;
        float v = (k < 1024) ? Wg[k * 1024 + dw] : Ug[(k - 1024) * 1024 + dw];
        int boff = ((cl << 12) | (k << 1)) ^ ((cl & 7) << 4);
        *(ushort*)((char*)Bl + boff) = f2bf(v);
    }

    const int lane = tid & 63;
    const int w  = tid >> 6;                 // wave 0..7
    const int wr = w & 3;                    // row quarter: rows wr*16..wr*16+15
    const int kh = w >> 2;                   // K-half: 0 or 1
    const int lx = lane & 15;
    const int qq = lane >> 4;
    const int kg = qq * 8;
    const int lr = wr * 16 + lx;             // local row within row-group
    const int brow = rg * 64 + lr;           // global batch row

    const int bofs0 = (lx << 12) ^ ((lx & 7) << 4);
    const int bofs1 = ((16 + lx) << 12) ^ ((lx & 7) << 4);

    const int kb    = kh * 512;              // K-half base (within x or h range)
    const int fbase = kh * 64;               // producer flag/chunk base for h half
    float* myPre = kh ? pre1 : pre0;
    const int r0 = wr * 16 + qq * 4;         // C/D row base (col = lx, row = r0+reg)

    // gate-phase mapping: 1 state per thread: row = tid>>3, dd = tid&7
    const int grow_ = tid >> 3;
    const int gdd   = tid & 7;
    const int gd    = cb * 8 + gdd;
    const float bF = bfp[gd], bI = bip[gd], bO = bop[gd], bC = bcp[gd];

    float cst = 0.f;
    int* myflags = flags + rg * 128;
    int fidx = feats[brow * SEQ];

    __syncthreads();   // Bl ready

    for (int t = 0; t < SEQ; t++) {
        f32x4 a00 = {0,0,0,0}, a01 = {0,0,0,0};   // n-tile 0, even/odd k-step
        f32x4 a10 = {0,0,0,0}, a11 = {0,0,0,0};   // n-tile 1, even/odd k-step

        // ---- x @ W, my K-half: k = kb .. kb+511 (16 k-steps) ----
        {
            const ushort* xrow = emb + (size_t)fidx * DIMS;
            fidx = (t + 1 < SEQ) ? feats[brow * SEQ + t + 1] : 0;
            #pragma unroll 4
            for (int ks = 0; ks < 16; ks += 2) {
                {
                    int k = kb + ks * 32 + kg;
                    short8 a  = *(const short8*)(xrow + k);
                    short8 b0 = *(const short8*)((const char*)Bl + (bofs0 ^ (k << 1)));
                    short8 b1 = *(const short8*)((const char*)Bl + (bofs1 ^ (k << 1)));
                    a00 = __builtin_amdgcn_mfma_f32_16x16x32_bf16(a, b0, a00, 0, 0, 0);
                    a10 = __builtin_amdgcn_mfma_f32_16x16x32_bf16(a, b1, a10, 0, 0, 0);
                }
                {
                    int k = kb + (ks + 1) * 32 + kg;
                    short8 a  = *(const short8*)(xrow + k);
                    short8 b0 = *(const short8*)((const char*)Bl + (bofs0 ^ (k << 1)));
                    short8 b1 = *(const short8*)((const char*)Bl + (bofs1 ^ (k << 1)));
                    a01 = __builtin_amdgcn_mfma_f32_16x16x32_bf16(a, b0, a01, 0, 0, 0);
                    a11 = __builtin_amdgcn_mfma_f32_16x16x32_bf16(a, b1, a11, 0, 0, 0);
                }
            }
        }

        if (t > 0) {
            // ---- poll my K-half's 64 producers (1 flag per lane) ----
            long guard = 0;
            for (;;) {
                int f0 = __hip_atomic_load(myflags + fbase + lane, __ATOMIC_RELAXED, __HIP_MEMORY_SCOPE_AGENT);
                if (__all(f0 >= t)) break;
                __builtin_amdgcn_s_sleep(1);
                if (++guard > 100000000L) break;  // deadlock safety valve
            }
            // ---- h @ U, my K-half: 16 k-steps, same accumulators ----
            const ushort* hbase = hbuf + (size_t)((t & 1) * 2 + rg) * (128 * 512);
            #pragma unroll 4
            for (int ks = 0; ks < 16; ks += 2) {
                {
                    int chunk = fbase + ks * 4 + qq;
                    const unsigned long long* hp =
                        (const unsigned long long*)(hbase + (chunk << 9) + lr * 8);
                    union { unsigned long long u[2]; short8 v; } av;
                    av.u[0] = __hip_atomic_load(hp,     __ATOMIC_RELAXED, __HIP_MEMORY_SCOPE_AGENT);
                    av.u[1] = __hip_atomic_load(hp + 1, __ATOMIC_RELAXED, __HIP_MEMORY_SCOPE_AGENT);
                    int k = 1024 + kb + ks * 32 + kg;
                    short8 b0 = *(const short8*)((const char*)Bl + (bofs0 ^ (k << 1)));
                    short8 b1 = *(const short8*)((const char*)Bl + (bofs1 ^ (k << 1)));
                    a00 = __builtin_amdgcn_mfma_f32_16x16x32_bf16(av.v, b0, a00, 0, 0, 0);
                    a10 = __builtin_amdgcn_mfma_f32_16x16x32_bf16(av.v, b1, a10, 0, 0, 0);
                }
                {
                    int chunk = fbase + (ks + 1) * 4 + qq;
                    const unsigned long long* hp =
                        (const unsigned long long*)(hbase + (chunk << 9) + lr * 8);
                    union { unsigned long long u[2]; short8 v; } av;
                    av.u[0] = __hip_atomic_load(hp,     __ATOMIC_RELAXED, __HIP_MEMORY_SCOPE_AGENT);
                    av.u[1] = __hip_atomic_load(hp + 1, __ATOMIC_RELAXED, __HIP_MEMORY_SCOPE_AGENT);
                    int k = 1024 + kb + (ks + 1) * 32 + kg;
                    short8 b0 = *(const short8*)((const char*)Bl + (bofs0 ^ (k << 1)));
                    short8 b1 = *(const short8*)((const char*)Bl + (bofs1 ^ (k << 1)));
                    a01 = __builtin_amdgcn_mfma_f32_16x16x32_bf16(av.v, b0, a01, 0, 0, 0);
                    a11 = __builtin_amdgcn_mfma_f32_16x16x32_bf16(av.v, b1, a11, 0, 0, 0);
                }
            }
        }

        // ---- write partials (C/D layout: col = lane&15, row = (lane>>4)*4 + reg) ----
        #pragma unroll
        for (int j = 0; j < 4; j++) {
            myPre[(r0 + j) * 36 + lx]      = a00[j] + a01[j];
            myPre[(r0 + j) * 36 + 16 + lx] = a10[j] + a11[j];
        }
        __syncthreads();   // sync A: pre0 + pre1 complete

        // ---- gates: 1 state per thread ----
        {
            int base = grow_ * 36;
            float pf = pre0[base + gdd]      + pre1[base + gdd]      + bF;
            float pi = pre0[base + 8 + gdd]  + pre1[base + 8 + gdd]  + bI;
            float po = pre0[base + 16 + gdd] + pre1[base + 16 + gdd] + bO;
            float pc = pre0[base + 24 + gdd] + pre1[base + 24 + gdd] + bC;
            float f  = 1.f / (1.f + __expf(-pf));
            float ig = 1.f / (1.f + __expf(-pi));
            float o  = 1.f / (1.f + __expf(-po));
            float e2 = __expf(2.f * pc);
            float cc = (e2 - 1.f) / (e2 + 1.f);
            float cn = f * cst + ig * cc;
            cst = cn;
            float e2c = __expf(2.f * cn);
            float th  = (e2c - 1.f) / (e2c + 1.f);
            float h   = o * th;
            if (t < SEQ - 1) {
                // coalesced: thread tid -> hnext[cb*512 + tid]
                ushort* hw = hbuf + (size_t)(((t + 1) & 1) * 2 + rg) * (128 * 512) + cb * 512 + tid;
                __hip_atomic_store(hw, f2bf(h), __ATOMIC_RELAXED, __HIP_MEMORY_SCOPE_AGENT);
            } else {
                int gr = rg * 64 + grow_;
                out[gr * 2048 + gd] = h;
                out[gr * 2048 + 1024 + gd] = cn;
            }
        }

        if (t < SEQ - 1) {
            asm volatile("s_waitcnt vmcnt(0)" ::: "memory");  // h stores acked at coherence point
            __syncthreads();                                   // sync B: publishes done; pre[] reusable
            if (tid == 0) {
                __hip_atomic_store(myflags + cb, t + 1, __ATOMIC_RELAXED, __HIP_MEMORY_SCOPE_AGENT);
            }
        }
    }
}

extern "C" void kernel_launch(void* const* d_in, const int* in_sizes, int n_in,
                              void* d_out, int out_size, void* d_ws, size_t ws_size,
                              hipStream_t stream) {
    const int*   feats = (const int*)d_in[0];
    const float* emb_f = (const float*)d_in[1];
    const float* Wf = (const float*)d_in[2];
    const float* Uf = (const float*)d_in[3];
    const float* bf_ = (const float*)d_in[4];
    const float* Wi = (const float*)d_in[5];
    const float* Ui = (const float*)d_in[6];
    const float* bi_ = (const float*)d_in[7];
    const float* Wo = (const float*)d_in[8];
    const float* Uo = (const float*)d_in[9];
    const float* bo_ = (const float*)d_in[10];
    const float* Wc = (const float*)d_in[11];
    const float* Uc = (const float*)d_in[12];
    const float* bc_ = (const float*)d_in[13];

    char* ws = (char*)d_ws;
    ushort* emb_bf = (ushort*)ws;                          // 65,536,000 B
    ushort* hbuf   = (ushort*)(ws + 65536000);             // 2x2x128x64x8 bf16 = 524,288 B
    int*    flags  = (int*)(ws + 65536000 + 524288);       // 256 flags

    hipMemsetAsync(flags, 0, 1024, stream);
    conv_emb_kernel<<<1024, 256, 0, stream>>>(emb_f, emb_bf, VOCAB * DIMS);
    lstm_kernel<<<GRID, 512, 0, stream>>>(feats, emb_bf,
                                          Wf, Uf, bf_, Wi, Ui, bi_,
                                          Wo, Uo, bo_, Wc, Uc, bc_,
                                          hbuf, (float*)d_out, flags);
}